// Round 7
// baseline (221.868 us; speedup 1.0000x reference)
//
#include <hip/hip_runtime.h>
#include <hip/hip_bf16.h>

#define N_NODES 100000
#define N_EDGES 1600000
#define IN_F 256
#define OUT_F 128

#define NBUCK 782          // ceil(100000 / 128), 128 rows per parent bucket
#define CH 4096            // edges per bscatter block
#define NCHB ((N_EDGES + CH - 1) / CH)   // 391
#define SRTC 4096          // bsort chunk capacity

typedef __attribute__((ext_vector_type(8))) short bhalf8;
typedef __attribute__((ext_vector_type(4))) float f32x4;

static __device__ __forceinline__ unsigned short f2bfs(float f) {
    __hip_bfloat16 h = __float2bfloat16(f);
    return *reinterpret_cast<unsigned short*>(&h);
}

// ---------------- W^T pre-pass: Wt[col][k] = bf16(W[k][col]) ----------------
__global__ __launch_bounds__(256) void wt_kernel(
    const float* __restrict__ W, unsigned short* __restrict__ Wt)
{
    const int idx = blockIdx.x * 256 + threadIdx.x;
    const int col = idx >> 8;
    const int k   = idx & 255;
    Wt[idx] = f2bfs(W[(size_t)k * OUT_F + col]);
}

// ---------------- MFMA GEMM: support(bf16) = x @ W ----------------
__global__ __launch_bounds__(256) void gemm_mfma_kernel(
    const float* __restrict__ x, const unsigned short* __restrict__ Wt,
    unsigned short* __restrict__ support)
{
    __shared__ unsigned short Bs[128 * 256];   // 64 KB

    const int tid = threadIdx.x;
    {
        const int row  = tid >> 1;
        const int half = tid & 1;
        const uint4* src = (const uint4*)(Wt + (size_t)row * 256 + half * 128);
        uint4* dstbase   = (uint4*)(Bs + (size_t)row * 256 + half * 128);
        const int sw = row & 7;
        #pragma unroll
        for (int i = 0; i < 16; ++i)
            dstbase[i ^ sw] = src[i];
    }
    __syncthreads();

    const int wave = tid >> 6, lane = tid & 63;
    const int r_lo = lane & 15;
    const int kq   = lane >> 4;
    const int row0 = blockIdx.x * 128 + wave * 32;

    const float* xa0 = x + (size_t)min(row0 + r_lo,      N_NODES - 1) * IN_F + kq * 8;
    const float* xa1 = x + (size_t)min(row0 + 16 + r_lo, N_NODES - 1) * IN_F + kq * 8;

    f32x4 acc[2][8];
    #pragma unroll
    for (int f = 0; f < 2; ++f)
        #pragma unroll
        for (int c = 0; c < 8; ++c) acc[f][c] = (f32x4)0.f;

    #pragma unroll
    for (int ks = 0; ks < 8; ++ks) {
        const float4 a0l = *(const float4*)(xa0 + ks * 32);
        const float4 a0h = *(const float4*)(xa0 + ks * 32 + 4);
        const float4 a1l = *(const float4*)(xa1 + ks * 32);
        const float4 a1h = *(const float4*)(xa1 + ks * 32 + 4);

        bhalf8 A0, A1;
        A0[0] = (short)f2bfs(a0l.x); A0[1] = (short)f2bfs(a0l.y);
        A0[2] = (short)f2bfs(a0l.z); A0[3] = (short)f2bfs(a0l.w);
        A0[4] = (short)f2bfs(a0h.x); A0[5] = (short)f2bfs(a0h.y);
        A0[6] = (short)f2bfs(a0h.z); A0[7] = (short)f2bfs(a0h.w);
        A1[0] = (short)f2bfs(a1l.x); A1[1] = (short)f2bfs(a1l.y);
        A1[2] = (short)f2bfs(a1l.z); A1[3] = (short)f2bfs(a1l.w);
        A1[4] = (short)f2bfs(a1h.x); A1[5] = (short)f2bfs(a1h.y);
        A1[6] = (short)f2bfs(a1h.z); A1[7] = (short)f2bfs(a1h.w);

        #pragma unroll
        for (int cf = 0; cf < 8; ++cf) {
            const int col = cf * 16 + r_lo;
            const int off = ((ks * 32 + kq * 8) ^ ((col & 7) << 3));
            const bhalf8 B = *(const bhalf8*)(Bs + (size_t)col * 256 + off);
            acc[0][cf] = __builtin_amdgcn_mfma_f32_16x16x32_bf16(A0, B, acc[0][cf], 0, 0, 0);
            acc[1][cf] = __builtin_amdgcn_mfma_f32_16x16x32_bf16(A1, B, acc[1][cf], 0, 0, 0);
        }
    }

    #pragma unroll
    for (int f = 0; f < 2; ++f)
        #pragma unroll
        for (int r = 0; r < 4; ++r) {
            const int row = row0 + f * 16 + kq * 4 + r;
            if (row < N_NODES) {
                unsigned short* dst = support + (size_t)row * OUT_F + r_lo;
                #pragma unroll
                for (int cf = 0; cf < 8; ++cf)
                    dst[cf * 16] = f2bfs(acc[f][cf][r]);
            }
        }
}

// ---------------- row histogram ----------------
__global__ __launch_bounds__(256) void hist_kernel(
    const int* __restrict__ erow, int* __restrict__ counts)
{
    const int e = blockIdx.x * blockDim.x + threadIdx.x;
    if (e < N_EDGES) atomicAdd(&counts[erow[e]], 1);
}

// ---------------- 3-phase coalesced scan over 100k counts ----------------
#define SB 1024
#define NB ((N_NODES + SB - 1) / SB)    // 98

__global__ __launch_bounds__(SB) void scan1_kernel(
    const int* __restrict__ counts, int* __restrict__ incl, int* __restrict__ partials)
{
    __shared__ int s[SB];
    const int tid = threadIdx.x;
    const int i   = blockIdx.x * SB + tid;
    const int v   = (i < N_NODES) ? counts[i] : 0;
    s[tid] = v;
    __syncthreads();
    for (int off = 1; off < SB; off <<= 1) {
        const int a = (tid >= off) ? s[tid - off] : 0;
        const int t = s[tid];
        __syncthreads();
        s[tid] = t + a;
        __syncthreads();
    }
    if (i < N_NODES) incl[i] = s[tid];
    if (tid == SB - 1) partials[blockIdx.x] = s[SB - 1];
}

__global__ __launch_bounds__(128) void scan2_kernel(int* __restrict__ partials)
{
    __shared__ int s[128];
    const int t = threadIdx.x;
    const int v = (t < NB) ? partials[t] : 0;
    s[t] = v;
    __syncthreads();
    for (int off = 1; off < 128; off <<= 1) {
        const int a  = (t >= off) ? s[t - off] : 0;
        const int x0 = s[t];
        __syncthreads();
        s[t] = x0 + a;
        __syncthreads();
    }
    if (t < NB) partials[t] = s[t] - v;      // exclusive
    if (t == 127) partials[NB] = s[127];     // grand total
}

// writes row offsets + row cursors + bucket offsets + bucket cursors
__global__ __launch_bounds__(SB) void scan3_kernel(
    const int* __restrict__ counts, const int* __restrict__ incl,
    const int* __restrict__ partials, int* __restrict__ offsets,
    int* __restrict__ rowcur, int* __restrict__ boffs, int* __restrict__ bcur)
{
    const int i = blockIdx.x * SB + threadIdx.x;
    if (i < N_NODES) {
        const int off = incl[i] - counts[i] + partials[blockIdx.x];
        offsets[i] = off;
        rowcur[i]  = off;
        if ((i & 127) == 0) { boffs[i >> 7] = off; bcur[i >> 7] = off; }
    }
    if (i == 0) { offsets[N_NODES] = partials[NB]; boffs[NBUCK] = partials[NB]; }
}

// ---------------- bucket scatter: group edges by 128-row bucket ----------------
__global__ __launch_bounds__(256) void bscatter_kernel(
    const int* __restrict__ erow, const int* __restrict__ ecol,
    const float* __restrict__ eval, int* __restrict__ bcur,
    int2* __restrict__ ebuf)
{
    __shared__ int h[NBUCK];
    __shared__ int cur[NBUCK];
    __shared__ int gbase[NBUCK];
    __shared__ int ps[256];
    __shared__ unsigned short bb[CH];
    __shared__ int2 buf[CH];

    const int tid = threadIdx.x;
    const int e0  = blockIdx.x * CH;
    const int e1  = min(e0 + CH, N_EDGES);
    const int n   = e1 - e0;

    for (int i = tid; i < NBUCK; i += 256) h[i] = 0;
    __syncthreads();

    for (int e = e0 + tid; e < e1; e += 256)
        atomicAdd(&h[erow[e] >> 7], 1);
    __syncthreads();

    {
        const int idx0 = tid * 4;
        int sum = 0;
        #pragma unroll
        for (int k = 0; k < 4; ++k) { const int ii = idx0 + k; if (ii < NBUCK) sum += h[ii]; }
        ps[tid] = sum;
        __syncthreads();
        for (int off = 1; off < 256; off <<= 1) {
            const int a  = (tid >= off) ? ps[tid - off] : 0;
            const int x0 = ps[tid];
            __syncthreads();
            ps[tid] = x0 + a;
            __syncthreads();
        }
        int run = (tid == 0) ? 0 : ps[tid - 1];
        #pragma unroll
        for (int k = 0; k < 4; ++k) {
            const int ii = idx0 + k;
            if (ii < NBUCK) { cur[ii] = run; run += h[ii]; }
        }
    }
    __syncthreads();

    for (int e = e0 + tid; e < e1; e += 256) {
        const int r = erow[e];
        const int b = r >> 7;
        const int p = atomicAdd(&cur[b], 1);
        buf[p] = make_int2(((r & 127) << 17) | ecol[e], __float_as_int(eval[e]));
        bb[p]  = (unsigned short)b;
    }
    __syncthreads();

    for (int i = tid; i < NBUCK; i += 256)
        gbase[i] = h[i] ? atomicAdd(&bcur[i], h[i]) : 0;
    __syncthreads();

    for (int i = tid; i < n; i += 256) {
        const int b  = bb[i];
        const int lb = cur[b] - h[b];
        ebuf[gbase[b] + (i - lb)] = buf[i];
    }
}

// ---------------- bsort: bucket-grouped -> fully row-grouped (col,val) ----------------
__global__ __launch_bounds__(256) void bsort_kernel(
    const int* __restrict__ boffs, const int2* __restrict__ ebuf,
    int* __restrict__ rowcur, int2* __restrict__ ebuf2)
{
    __shared__ int2 srt[SRTC];   // 32 KB
    __shared__ int rc[128];
    __shared__ int rb[129];
    __shared__ int cc[128];
    __shared__ int gb[128];

    const int b    = blockIdx.x;
    const int beg  = boffs[b];
    const int end  = boffs[b + 1];
    const int row0 = b << 7;
    const int tid  = threadIdx.x;

    for (int cbeg = beg; cbeg < end; cbeg += SRTC) {
        const int nin = min(end - cbeg, SRTC);

        if (tid < 128) rc[tid] = 0;
        __syncthreads();
        for (int i = tid; i < nin; i += 256)
            atomicAdd(&rc[(unsigned)ebuf[cbeg + i].x >> 17], 1);
        __syncthreads();

        if (tid < 128) cc[tid] = rc[tid];
        __syncthreads();
        for (int off = 1; off < 128; off <<= 1) {
            int a = 0;
            if (tid < 128) a = (tid >= off) ? cc[tid - off] : 0;
            __syncthreads();
            if (tid < 128) cc[tid] += a;
            __syncthreads();
        }
        if (tid < 128) { rb[tid + 1] = cc[tid]; cc[tid] -= rc[tid]; }
        if (tid == 0) rb[0] = 0;
        __syncthreads();

        for (int i = tid; i < nin; i += 256) {
            const int2 e = ebuf[cbeg + i];
            srt[atomicAdd(&cc[(unsigned)e.x >> 17], 1)] = e;
        }
        __syncthreads();

        if (tid < 128)
            gb[tid] = rc[tid] ? atomicAdd(&rowcur[row0 + tid], rc[tid]) : 0;
        __syncthreads();

        for (int i = tid; i < nin; i += 256) {
            const int2 e  = srt[i];
            const int  lr = (unsigned)e.x >> 17;
            ebuf2[gb[lr] + (i - rb[lr])] = make_int2(e.x & 0x1FFFF, e.y);
        }
        __syncthreads();
    }
}

// ---------------- rspmm: one wave per row, register acc, no barriers ----------------
__global__ __launch_bounds__(256) void rspmm_kernel(
    const int* __restrict__ offsets, const int2* __restrict__ ebuf2,
    const unsigned short* __restrict__ support,
    const float* __restrict__ bias, float* __restrict__ out)
{
    const int row  = blockIdx.x * 4 + (threadIdx.x >> 6);
    const int lane = threadIdx.x & 63;
    const int beg  = offsets[row];
    const int end  = offsets[row + 1];

    float a0 = 0.f, a1 = 0.f;
    int j = beg;
    for (; j + 4 <= end; j += 4) {
        const int2 e0 = ebuf2[j],     e1 = ebuf2[j + 1];
        const int2 e2 = ebuf2[j + 2], e3 = ebuf2[j + 3];
        const unsigned u0 = *(const unsigned*)(support + ((size_t)e0.x << 7) + lane * 2);
        const unsigned u1 = *(const unsigned*)(support + ((size_t)e1.x << 7) + lane * 2);
        const unsigned u2 = *(const unsigned*)(support + ((size_t)e2.x << 7) + lane * 2);
        const unsigned u3 = *(const unsigned*)(support + ((size_t)e3.x << 7) + lane * 2);
        const float v0 = __int_as_float(e0.y), v1 = __int_as_float(e1.y);
        const float v2 = __int_as_float(e2.y), v3 = __int_as_float(e3.y);
        a0 += v0 * __uint_as_float(u0 << 16);
        a1 += v0 * __uint_as_float(u0 & 0xFFFF0000u);
        a0 += v1 * __uint_as_float(u1 << 16);
        a1 += v1 * __uint_as_float(u1 & 0xFFFF0000u);
        a0 += v2 * __uint_as_float(u2 << 16);
        a1 += v2 * __uint_as_float(u2 & 0xFFFF0000u);
        a0 += v3 * __uint_as_float(u3 << 16);
        a1 += v3 * __uint_as_float(u3 & 0xFFFF0000u);
    }
    for (; j < end; ++j) {
        const int2 e = ebuf2[j];
        const unsigned u = *(const unsigned*)(support + ((size_t)e.x << 7) + lane * 2);
        const float v = __int_as_float(e.y);
        a0 += v * __uint_as_float(u << 16);
        a1 += v * __uint_as_float(u & 0xFFFF0000u);
    }
    const float2 bv = ((const float2*)bias)[lane];
    ((float2*)(out + ((size_t)row << 7)))[lane] = make_float2(a0 + bv.x, a1 + bv.y);
}

extern "C" void kernel_launch(void* const* d_in, const int* in_sizes, int n_in,
                              void* d_out, int out_size, void* d_ws, size_t ws_size,
                              hipStream_t stream) {
    const float* x    = (const float*)d_in[0];
    const int*   erow = (const int*)  d_in[1];
    const int*   ecol = (const int*)  d_in[2];
    const float* eval = (const float*)d_in[3];
    const float* W    = (const float*)d_in[4];
    const float* bias = (const float*)d_in[5];
    float*       out  = (float*)d_out;

    // workspace layout (16B-aligned chunks)
    char* ws = (char*)d_ws;
    unsigned short* support = (unsigned short*)ws; ws += (size_t)N_NODES * OUT_F * 2;  // 25.6 MB
    unsigned short* Wt      = (unsigned short*)ws; ws += (size_t)OUT_F * IN_F * 2;     // 64 KB
    int*  counts  = (int*)ws;                      ws += (size_t)(N_NODES + 8) * 4;
    int*  incl    = (int*)ws;                      ws += (size_t)(N_NODES + 8) * 4;
    int*  offsets = (int*)ws;                      ws += (size_t)(N_NODES + 8) * 4;
    int*  rowcur  = (int*)ws;                      ws += (size_t)(N_NODES + 8) * 4;
    int*  partials= (int*)ws;                      ws += (size_t)(NB + 8) * 4;
    int*  boffs   = (int*)ws;                      ws += (size_t)(NBUCK + 8) * 4;
    int*  bcur    = (int*)ws;                      ws += (size_t)(NBUCK + 8) * 4;
    int2* ebuf    = (int2*)ws;                     ws += (size_t)N_EDGES * 8;           // 12.8 MB
    int2* ebuf2   = (int2*)ws;                     ws += (size_t)N_EDGES * 8;           // 12.8 MB

    hipMemsetAsync(counts, 0, (size_t)N_NODES * 4, stream);

    wt_kernel<<<(OUT_F * IN_F) / 256, 256, 0, stream>>>(W, Wt);
    gemm_mfma_kernel<<<(N_NODES + 127) / 128, 256, 0, stream>>>(x, Wt, support);

    hist_kernel<<<(N_EDGES + 255) / 256, 256, 0, stream>>>(erow, counts);
    scan1_kernel<<<NB, SB, 0, stream>>>(counts, incl, partials);
    scan2_kernel<<<1, 128, 0, stream>>>(partials);
    scan3_kernel<<<NB, SB, 0, stream>>>(counts, incl, partials, offsets,
                                        rowcur, boffs, bcur);

    bscatter_kernel<<<NCHB, 256, 0, stream>>>(erow, ecol, eval, bcur, ebuf);
    bsort_kernel<<<NBUCK, 256, 0, stream>>>(boffs, ebuf, rowcur, ebuf2);

    rspmm_kernel<<<N_NODES / 4, 256, 0, stream>>>(offsets, ebuf2, support, bias, out);
}